// Round 5
// baseline (168625.403 us; speedup 1.0000x reference)
//
#include <hip/hip_runtime.h>
#include <math.h>

// Problem constants
#define Bsz   256
#define Hd    512
#define Din   512
#define Lenc  48
#define Look  10
#define G4    2048     // 4*H
#define LabStride 58   // LENC + LDEC
#define StartIdx  48   // LDEC + LENC - LOOK

typedef unsigned short u16;
using bfrag = __attribute__((ext_vector_type(8))) short;   // 8 bf16 (4 VGPRs)
using f32x4 = __attribute__((ext_vector_type(4))) float;   // 4 fp32 acc

#define MFMA16(a,b,c) __builtin_amdgcn_mfma_f32_16x16x32_bf16((a),(b),(c),0,0,0)

__device__ __forceinline__ u16 f2bf(float f){
  unsigned u = __float_as_uint(f);
  u += 0x7FFFu + ((u>>16)&1u);               // RNE
  return (u16)(u>>16);
}
__device__ __forceinline__ float bf2f(u16 h){ return __uint_as_float(((unsigned)h)<<16); }
__device__ __forceinline__ float sigm(float x){ return 1.f/(1.f+__expf(-x)); }

// ---- 32x32 output tile per wave (M=32), K-loop of 16x16x32 MFMAs ----
// A: activations [m][k] row-major (lda), W: weights [n][k] row-major (ldw) == B^T.
// Frag layout (m89/m91): A row = lane&15, k = 8*(lane>>4)+j ; same for W (row->n).
// acc[4] = [mi*2+ni], D: col(n)=lane&15, row(m)=4*(lane>>4)+reg.
template<int K>
__device__ __forceinline__ void mm32(const u16* __restrict__ A, int lda,
                                     const u16* __restrict__ W, int ldw,
                                     f32x4* acc, int lane){
  const int rr = lane & 15, ko = (lane>>4)<<3;
  const u16* a0 = A + (size_t)rr*lda + ko;
  const u16* a1 = a0 + 16*(size_t)lda;
  const u16* w0 = W + (size_t)rr*ldw + ko;
  const u16* w1 = w0 + 16*(size_t)ldw;
#pragma unroll
  for(int k=0;k<K;k+=32){
    bfrag av0 = *(const bfrag*)(a0+k);
    bfrag av1 = *(const bfrag*)(a1+k);
    bfrag wv0 = *(const bfrag*)(w0+k);
    bfrag wv1 = *(const bfrag*)(w1+k);
    acc[0] = MFMA16(av0,wv0,acc[0]);
    acc[1] = MFMA16(av0,wv1,acc[1]);
    acc[2] = MFMA16(av1,wv0,acc[2]);
    acc[3] = MFMA16(av1,wv1,acc[3]);
  }
}

// ---- M=16 x N=16*NT tile per wave, K=512. A global (lda=512), W in LDS (pitch LP).
// acc[n]: D row=4*(lane>>4)+j, col = n-tile col (lane&15).
template<int NT,int LP>
__device__ __forceinline__ void mmGL(const u16* __restrict__ A, const u16* W,
                                     f32x4* acc, int lane){
  const int rr=lane&15, ko=(lane>>4)<<3;
  const u16* a0=A+(size_t)rr*512+ko;
  const u16* w0=W+rr*LP+ko;
#pragma unroll
  for(int k=0;k<512;k+=32){
    bfrag av=*(const bfrag*)(a0+k);
#pragma unroll
    for(int n=0;n<NT;n++){
      bfrag wvv=*(const bfrag*)(w0+n*16*LP+k);
      acc[n]=MFMA16(av,wvv,acc[n]);
    }
  }
}

// ---- device-scope grid barrier (all 256 blocks co-resident, monotone counter) ----
__device__ __forceinline__ void gbar(unsigned* bar){
  __syncthreads();
  __threadfence();                               // release: flush my stores (L2 wb)
  if(threadIdx.x==0){
    unsigned old=__hip_atomic_fetch_add(bar,1u,__ATOMIC_ACQ_REL,__HIP_MEMORY_SCOPE_AGENT);
    unsigned tgt=(old/256u+1u)*256u;
    while(__hip_atomic_load(bar,__ATOMIC_ACQUIRE,__HIP_MEMORY_SCOPE_AGENT)<tgt)
      __builtin_amdgcn_s_sleep(8);
  }
  __syncthreads();
  __threadfence();                               // acquire: invalidate stale lines
}

// ---------------- setup kernels ----------------
__global__ void k_cvt(const float* __restrict__ s, u16* __restrict__ d, int n){
  for(int i=blockIdx.x*blockDim.x+threadIdx.x; i<n; i+=gridDim.x*blockDim.x) d[i]=f2bf(s[i]);
}

// Wih_tg is (2048 x 513): col0 -> c0 (fp32), cols 1..512 -> packed bf16
__global__ void k_cvt_tg(const float* __restrict__ s, u16* __restrict__ d, float* __restrict__ c0){
  int stride=gridDim.x*blockDim.x;
  for(int i=blockIdx.x*blockDim.x+threadIdx.x; i<G4*Hd; i+=stride){
    int n=i>>9, k=i&511;
    d[i]=f2bf(s[n*513+1+k]);
  }
  for(int n=blockIdx.x*blockDim.x+threadIdx.x; n<G4; n+=stride) c0[n]=s[n*513];
}

__global__ void k_init(const float* __restrict__ label, float* __restrict__ lab){
  int b=threadIdx.x;
  if(b<Bsz) lab[b]=label[b*LabStride+StartIdx];
}

// wi_seq[l][b][h] = input[b][l][:] . Wi_w[h][:] + Wi_b[h]
__global__ __launch_bounds__(64) void k_wi(const u16* __restrict__ inpb, const u16* __restrict__ Wi,
                     const float* __restrict__ Wib, float* __restrict__ wi_seq){
  int lane=threadIdx.x;
  int r0=blockIdx.x*32, h0=blockIdx.y*32;
  f32x4 acc[4]={};
  mm32<Din>(inpb+(size_t)r0*Din, Din, Wi+(size_t)h0*Din, Din, acc, lane);
  int cr=(lane>>4)*4, cc=lane&15;
  for(int mi=0;mi<2;mi++)for(int ni=0;ni<2;ni++){
    int h=h0+ni*16+cc; float bias=Wib[h];
    f32x4 a=acc[mi*2+ni];
    for(int j=0;j<4;j++){
      int g=r0+mi*16+cr+j;
      int b=g/Lenc, l=g-b*Lenc;
      wi_seq[((size_t)l*Bsz+b)*Hd + h] = a[j]+bias;
    }
  }
}

// C = A1 @ W[:, :512]^T + A2 @ W[:, 512:]^T   (fp32 out; wt and wh)
__global__ __launch_bounds__(128) void k_dual(const u16* __restrict__ A1, const u16* __restrict__ A2,
      const u16* __restrict__ W, float* __restrict__ C){
  int lane=threadIdx.x&63, wid=threadIdx.x>>6;
  int b0=blockIdx.x*32, h0=blockIdx.y*32;
  f32x4 acc[4]={};
  if(wid==0) mm32<Hd>(A1+(size_t)b0*Hd, Hd, W+(size_t)h0*1024,     1024, acc, lane);
  else       mm32<Hd>(A2+(size_t)b0*Hd, Hd, W+(size_t)h0*1024+512, 1024, acc, lane);
  __shared__ f32x4 red[4*64];
  if(wid==1){ for(int i=0;i<4;i++) red[i*64+lane]=acc[i]; }
  __syncthreads();
  if(wid!=0) return;
  for(int i=0;i<4;i++) acc[i]+=red[i*64+lane];
  int cr=(lane>>4)*4, cc=lane&15;
  for(int mi=0;mi<2;mi++)for(int ni=0;ni<2;ni++){
    int h=h0+ni*16+cc;
    f32x4 a=acc[mi*2+ni];
    for(int j=0;j<4;j++){
      int b=b0+mi*16+cr+j;
      C[(size_t)b*Hd+h]=a[j];
    }
  }
}

// ============ cooperative weights-stationary scan (one launch per outer step) ============
// 256 blocks x 512 thr (1/CU co-resident). Roles by bid>>6:
//  R0 (0-63):   spre. LDS: We slice [16 cols][1032] (he|ce halves).
//  R1 (64-127): score + softmax/xmod. LDS: Vd slice [16][520].
//  R2 (128-191): sp gates+cell. LDS: Wih_sp/Whh_sp gate-major [64][520] x2. c_sp in regs.
//  R3 (192-255): mid gates+cell (runs concurrent with next spre). c_mid in regs.
// Per block: cg=(bid&63)>>1 (col group of 16), mh=bid&1 (batch half of 128 rows).
__global__ __launch_bounds__(512,1) void k_coop(
    const float* __restrict__ finp, const float* __restrict__ wiseq,
    const float* __restrict__ wtf,
    const u16* __restrict__ web, const u16* __restrict__ vdb, const float* __restrict__ vd_b,
    const u16* __restrict__ wspih, const u16* __restrict__ wsphh,
    const float* __restrict__ bih_sp, const float* __restrict__ bhh_sp,
    const u16* __restrict__ wmidih, const u16* __restrict__ wmidhh,
    const float* __restrict__ bih_mid, const float* __restrict__ bhh_mid,
    u16* __restrict__ heA, u16* __restrict__ heB, u16* __restrict__ ceG,
    u16* __restrict__ spreG, float* __restrict__ scoreG, u16* __restrict__ xmodG,
    u16* __restrict__ hmA, u16* __restrict__ hmB,
    u16* __restrict__ mid2b, unsigned* bar)
{
  __shared__ __align__(16) u16 LB[66560];   // 133 KB
  __shared__ float sred[16];
  const int tid=threadIdx.x, lane=tid&63, wv=tid>>6;
  const int bid=blockIdx.x;
  const int role=bid>>6;
  const int q=bid&63, cg=q>>1, mh=q&1;
  const int r0 = mh*128 + wv*16;            // wave's 16-row M tile
  const int col = cg*16 + (lane&15);        // this thread's output column
  const int rj0 = r0 + 4*(lane>>4);         // first of this thread's 4 rows

  // ---- prologue: stage weights into LDS (once per launch) ----
  if(role==0){
    for(int i=tid;i<16*128;i+=512){ int rr=i>>7, cc=(i&127)*8;
      *(bfrag*)(LB + rr*1032 + cc) = *(const bfrag*)(web + ((size_t)(cg*16+rr))*1024 + cc); }
  } else if(role==1){
    for(int i=tid;i<16*64;i+=512){ int rr=i>>6, cc=(i&63)*8;
      *(bfrag*)(LB + rr*520 + cc) = *(const bfrag*)(vdb + ((size_t)(cg*16+rr))*512 + cc); }
  } else {
    const u16* Wi = (role==2)? wspih : wmidih;
    const u16* Wh = (role==2)? wsphh : wmidhh;
    for(int i=tid;i<64*64;i+=512){ int rr=i>>6, cc=(i&63)*8;
      int gt=rr>>4, lr=rr&15;
      *(bfrag*)(LB + rr*520 + cc)         = *(const bfrag*)(Wi + ((size_t)(gt*512 + cg*16 + lr))*512 + cc);
      *(bfrag*)(LB + 33280 + rr*520 + cc) = *(const bfrag*)(Wh + ((size_t)(gt*512 + cg*16 + lr))*512 + cc);
    }
  }
  // zero state arrays (256KB each = 65536 u32; 256 blocks x 256 u32)
  if(tid<256){
    ((unsigned*)heA)[(size_t)bid*256+tid]=0;
    ((unsigned*)heB)[(size_t)bid*256+tid]=0;
    ((unsigned*)ceG)[(size_t)bid*256+tid]=0;
    ((unsigned*)hmA)[(size_t)bid*256+tid]=0;
    ((unsigned*)hmB)[(size_t)bid*256+tid]=0;
  }
  // per-role constants
  float wt_r[4]={0,0,0,0}; float bi0=0,bi1=0,bi2=0,bi3=0,vbias=0;
  if(role==0){ for(int j=0;j<4;j++) wt_r[j]=wtf[(size_t)(rj0+j)*Hd + col]; }
  if(role==1){ vbias=vd_b[col]; }
  if(role==2){ bi0=bih_sp[col]+bhh_sp[col];           bi1=bih_sp[512+col]+bhh_sp[512+col];
               bi2=bih_sp[1024+col]+bhh_sp[1024+col]; bi3=bih_sp[1536+col]+bhh_sp[1536+col]; }
  if(role==3){ bi0=bih_mid[col]+bhh_mid[col];           bi1=bih_mid[512+col]+bhh_mid[512+col];
               bi2=bih_mid[1024+col]+bhh_mid[1024+col]; bi3=bih_mid[1536+col]+bhh_mid[1536+col]; }
  f32x4 cst={0.f,0.f,0.f,0.f};

  auto P1=[&](int ll){   // spre(ll) = tanh(he@We1 + ce@We2 + wi + wt)
    const u16* heR = (ll&1)? heB : heA;
    f32x4 a={0.f,0.f,0.f,0.f};
    mmGL<1,1032>(heR+(size_t)r0*Hd, LB,     &a, lane);
    mmGL<1,1032>(ceG+(size_t)r0*Hd, LB+512, &a, lane);
#pragma unroll
    for(int j=0;j<4;j++)
      spreG[(size_t)(rj0+j)*Hd+col] =
        f2bf(tanhf(a[j] + wiseq[((size_t)ll*Bsz + rj0+j)*Hd + col] + wt_r[j]));
  };

  gbar(bar);
  if(role==0) P1(0);
  gbar(bar);

  for(int l=0;l<Lenc;l++){
    const u16* heR = (l&1)? heB : heA;
    u16*       heW = (l&1)? heA : heB;
    const u16* hmR = (l&1)? hmB : hmA;
    u16*       hmW = (l&1)? hmA : hmB;

    if(role==1){  // P2: score slice
      f32x4 a={0.f,0.f,0.f,0.f};
      mmGL<1,520>(spreG+(size_t)r0*Hd, LB, &a, lane);
#pragma unroll
      for(int j=0;j<4;j++) scoreG[(size_t)(rj0+j)*Hd+col] = a[j]+vbias;
    }
    gbar(bar);

    if(role==1){  // P3: softmax rows [4q,4q+4) + xmod
      int row = 4*q + (tid>>7); int cid = tid&127;
      float sc[4], xv[4];
#pragma unroll
      for(int jj=0;jj<4;jj++){
        sc[jj]=scoreG[(size_t)row*Hd + cid+128*jj];
        xv[jj]=finp[((size_t)row*Lenc + l)*Din + cid+128*jj];
      }
      float m=fmaxf(fmaxf(sc[0],sc[1]),fmaxf(sc[2],sc[3]));
      for(int o=1;o<64;o<<=1) m=fmaxf(m,__shfl_xor(m,o));
      if(lane==0) sred[wv]=m;
      __syncthreads();
      m=fmaxf(sred[(tid>>7)*2], sred[(tid>>7)*2+1]);
      float e[4]; float s=0.f;
#pragma unroll
      for(int jj=0;jj<4;jj++){ e[jj]=__expf(sc[jj]-m); s+=e[jj]; }
      for(int o=1;o<64;o<<=1) s+=__shfl_xor(s,o);
      if(lane==0) sred[8+wv]=s;
      __syncthreads();
      s = sred[8+(tid>>7)*2] + sred[8+(tid>>7)*2+1];
      float inv=1.f/s;
#pragma unroll
      for(int jj=0;jj<4;jj++)
        xmodG[(size_t)row*Hd + cid+128*jj] = f2bf(xv[jj]*e[jj]*inv);
    }
    gbar(bar);

    if(role==2){  // P4: sp gates + cell -> heW, ceG
      f32x4 acc[4]={};
      mmGL<4,520>(xmodG+(size_t)r0*Hd, LB,       acc, lane);
      mmGL<4,520>(heR  +(size_t)r0*Hd, LB+33280, acc, lane);
#pragma unroll
      for(int j=0;j<4;j++){
        float ii=sigm(acc[0][j]+bi0), ff=sigm(acc[1][j]+bi1);
        float gg=tanhf(acc[2][j]+bi2), oo=sigm(acc[3][j]+bi3);
        float c2=ff*cst[j]+ii*gg; cst[j]=c2;
        heW[(size_t)(rj0+j)*Hd+col]=f2bf(oo*tanhf(c2));
        ceG[(size_t)(rj0+j)*Hd+col]=f2bf(c2);
      }
    }
    gbar(bar);

    if(role==0 && l<Lenc-1) P1(l+1);     // concurrent with P5
    if(role==3){  // P5: mid gates + cell -> hmW, mid2b[l]
      f32x4 acc[4]={};
      mmGL<4,520>(heW+(size_t)r0*Hd, LB,       acc, lane);   // x-input = he_l
      mmGL<4,520>(hmR+(size_t)r0*Hd, LB+33280, acc, lane);
#pragma unroll
      for(int j=0;j<4;j++){
        float ii=sigm(acc[0][j]+bi0), ff=sigm(acc[1][j]+bi1);
        float gg=tanhf(acc[2][j]+bi2), oo=sigm(acc[3][j]+bi3);
        float c2=ff*cst[j]+ii*gg; cst[j]=c2;
        u16 hb=f2bf(oo*tanhf(c2));
        hmW[(size_t)(rj0+j)*Hd+col]=hb;
        mid2b[((size_t)l*Bsz + rj0+j)*Hd + col]=hb;
      }
    }
    gbar(bar);
  }
}

// tg cell: x = [lab, dec_in] (col0 handled via c0 in epilogue)
__global__ __launch_bounds__(128) void k_tg(const u16* __restrict__ dec, const u16* __restrict__ ht,
    const u16* __restrict__ Wih, const u16* __restrict__ Whh,
    const float* __restrict__ c0, const float* __restrict__ bih, const float* __restrict__ bhh,
    const float* __restrict__ lab, float* __restrict__ cst, u16* __restrict__ cbf,
    u16* __restrict__ hout, int t0){
  int lane=threadIdx.x&63, wid=threadIdx.x>>6;
  int b0=blockIdx.x*32, h0=blockIdx.y*32;
  f32x4 acc[4][4]={};
  if(!t0){
    if(wid==0){ for(int g=0;g<4;g++) mm32<Hd>(dec+(size_t)b0*Hd, Hd, Wih+((size_t)g*Hd+h0)*Hd, Hd, acc[g], lane); }
    else      { for(int g=0;g<4;g++) mm32<Hd>(ht +(size_t)b0*Hd, Hd, Whh+((size_t)g*Hd+h0)*Hd, Hd, acc[g], lane); }
  }
  __shared__ f32x4 red[16*64];
  if(wid==1){ for(int i=0;i<16;i++) red[i*64+lane]=acc[i>>2][i&3]; }
  __syncthreads();
  if(wid!=0) return;
  for(int i=0;i<16;i++) acc[i>>2][i&3]+=red[i*64+lane];
  int cr=(lane>>4)*4, cc=lane&15;
  for(int mi=0;mi<2;mi++)for(int ni=0;ni<2;ni++){
    int h=h0+ni*16+cc; int tq=mi*2+ni;
    float bi =bih[h]+bhh[h];
    float bff=bih[Hd+h]+bhh[Hd+h];
    float bg =bih[2*Hd+h]+bhh[2*Hd+h];
    float bo =bih[3*Hd+h]+bhh[3*Hd+h];
    float ci=c0[h], cf=c0[Hd+h], cg2=c0[2*Hd+h], co=c0[3*Hd+h];
    for(int j=0;j<4;j++){
      int b=b0+mi*16+cr+j;
      size_t ix=(size_t)b*Hd+h;
      float lb=lab[b];
      float ii=sigm(acc[0][tq][j]+bi +lb*ci);
      float ff=sigm(acc[1][tq][j]+bff+lb*cf);
      float gg=tanhf(acc[2][tq][j]+bg +lb*cg2);
      float oo=sigm(acc[3][tq][j]+bo +lb*co);
      float cold=t0?0.f:cst[ix];
      float c2=ff*cold+ii*gg;
      float hv=oo*tanhf(c2);
      cst[ix]=c2; cbf[ix]=f2bf(c2); hout[ix]=f2bf(hv);
    }
  }
}

// target = ht @ reg_w^T + reg_b ; out[b*Look+t] and lab update
__global__ __launch_bounds__(64) void k_target(const u16* __restrict__ ht, const float* __restrict__ regw,
     const float* __restrict__ regb, float* __restrict__ outp, float* __restrict__ lab, int t){
  int b=blockIdx.x, lane=threadIdx.x;
  bfrag v=*(const bfrag*)(ht+(size_t)b*Hd+lane*8);
  const float* w=regw+lane*8;
  float a=0;
  for(int j=0;j<8;j++) a+=bf2f((u16)v[j])*w[j];
  for(int o=1;o<64;o<<=1) a+=__shfl_xor(a,o);
  if(lane==0){ float val=a+regb[0]; outp[b*Look+t]=val; lab[b]=val; }
}

// TT = tanh(mid2 @ Wx^T + wh[b] + Wx_b)
__global__ __launch_bounds__(128) void k_scgemm(const u16* __restrict__ mid2, const u16* __restrict__ Wx,
      const float* __restrict__ Wxb, const float* __restrict__ wh, u16* __restrict__ TT){
  int lane=threadIdx.x&63, wid=threadIdx.x>>6;
  int r0=blockIdx.x*32, h0=blockIdx.y*32;
  f32x4 acc[4]={};
  mm32<256>(mid2+(size_t)r0*Hd + wid*256, Hd, Wx+(size_t)h0*Hd + wid*256, Hd, acc, lane);
  __shared__ f32x4 red[4*64];
  if(wid==1){ for(int i=0;i<4;i++) red[i*64+lane]=acc[i]; }
  __syncthreads();
  if(wid!=0) return;
  for(int i=0;i<4;i++) acc[i]+=red[i*64+lane];
  int cr=(lane>>4)*4, cc=lane&15;
  for(int mi=0;mi<2;mi++)for(int ni=0;ni<2;ni++){
    int h=h0+ni*16+cc; float wb=Wxb[h];
    f32x4 a=acc[mi*2+ni];
    for(int j=0;j<4;j++){
      int row=r0+mi*16+cr+j;
      int b=row&255;
      TT[(size_t)row*Hd+h]=f2bf(tanhf(a[j]+wh[(size_t)b*Hd+h]+wb));
    }
  }
}

// sc[b][l] = TT[row] . V_w + V_b   (row = l*B + b)
__global__ __launch_bounds__(64) void k_scred(const u16* __restrict__ TT, const float* __restrict__ Vw,
      const float* __restrict__ Vb, float* __restrict__ sc){
  int row=blockIdx.x, lane=threadIdx.x;
  bfrag v=*(const bfrag*)(TT+(size_t)row*Hd+lane*8);
  const float* w=Vw+lane*8;
  float a=0;
  for(int j=0;j<8;j++) a+=bf2f((u16)v[j])*w[j];
  for(int o=1;o<64;o<<=1) a+=__shfl_xor(a,o);
  if(lane==0){ int l=row>>8, b=row&255; sc[b*Lenc+l]=a+Vb[0]; }
}

// dec_in[b][h] = sum_l sc[b][l] * mid2[l][b][h]
__global__ __launch_bounds__(256) void k_dec(const float* __restrict__ sc, const u16* __restrict__ mid2,
      u16* __restrict__ dec){
  __shared__ float s[Lenc];
  int b=blockIdx.x, tid=threadIdx.x;
  if(tid<Lenc) s[tid]=sc[b*Lenc+tid];
  __syncthreads();
  for(int h=tid; h<Hd; h+=256){
    float a=0;
    for(int l=0;l<Lenc;l++) a+=s[l]*bf2f(mid2[((size_t)l*Bsz+b)*Hd+h]);
    dec[(size_t)b*Hd+h]=f2bf(a);
  }
}

// ---------------- host ----------------
extern "C" void kernel_launch(void* const* d_in, const int* in_sizes, int n_in,
                              void* d_out, int out_size, void* d_ws, size_t ws_size,
                              hipStream_t stream){
  const float* f_inp    =(const float*)d_in[0];
  const float* f_label  =(const float*)d_in[1];
  const float* f_Wih_sp =(const float*)d_in[2];
  const float* f_Whh_sp =(const float*)d_in[3];
  const float* f_bih_sp =(const float*)d_in[4];
  const float* f_bhh_sp =(const float*)d_in[5];
  const float* f_Wih_tg =(const float*)d_in[6];
  const float* f_Whh_tg =(const float*)d_in[7];
  const float* f_bih_tg =(const float*)d_in[8];
  const float* f_bhh_tg =(const float*)d_in[9];
  const float* f_Wih_mid=(const float*)d_in[10];
  const float* f_Whh_mid=(const float*)d_in[11];
  const float* f_bih_mid=(const float*)d_in[12];
  const float* f_bhh_mid=(const float*)d_in[13];
  const float* f_Wi_w   =(const float*)d_in[14];
  const float* f_Wi_b   =(const float*)d_in[15];
  const float* f_We_w   =(const float*)d_in[16];
  const float* f_Wt_w   =(const float*)d_in[17];
  const float* f_Vd_w   =(const float*)d_in[18];
  const float* f_Vd_b   =(const float*)d_in[19];
  const float* f_Wx_w   =(const float*)d_in[20];
  const float* f_Wx_b   =(const float*)d_in[21];
  const float* f_Wh_w   =(const float*)d_in[22];
  const float* f_V_w    =(const float*)d_in[23];
  const float* f_V_b    =(const float*)d_in[24];
  const float* f_reg_w  =(const float*)d_in[25];
  const float* f_reg_b  =(const float*)d_in[26];
  float* outp=(float*)d_out;

  char* basep=(char*)d_ws; size_t off=0;
  auto alloc=[&](size_t bytes)->void*{ void* r=basep+off; off+=(bytes+255)&~((size_t)255); return r; };

  const size_t BH=(size_t)Bsz*Hd;
  u16*  wspih =(u16*)alloc((size_t)G4*Hd*2);
  u16*  wsphh =(u16*)alloc((size_t)G4*Hd*2);
  u16*  wtgih =(u16*)alloc((size_t)G4*Hd*2);
  u16*  wtghh =(u16*)alloc((size_t)G4*Hd*2);
  u16*  wmidih=(u16*)alloc((size_t)G4*Hd*2);
  u16*  wmidhh=(u16*)alloc((size_t)G4*Hd*2);
  u16*  web   =(u16*)alloc((size_t)Hd*1024*2);
  u16*  wtb   =(u16*)alloc((size_t)Hd*1024*2);
  u16*  whb   =(u16*)alloc((size_t)Hd*1024*2);
  u16*  vdb   =(u16*)alloc((size_t)Hd*Hd*2);
  u16*  wxb   =(u16*)alloc((size_t)Hd*Hd*2);
  u16*  wib   =(u16*)alloc((size_t)Hd*Hd*2);
  u16*  inpb  =(u16*)alloc((size_t)Bsz*Lenc*Din*2);
  float* c0f  =(float*)alloc((size_t)G4*4);
  float* wiseq=(float*)alloc((size_t)Lenc*BH*4);
  u16*  mid2b =(u16*)alloc((size_t)Lenc*BH*2);
  u16*  ttb   =(u16*)alloc((size_t)Lenc*BH*2);
  float* ctf  =(float*)alloc(BH*4);
  u16*  ctb   =(u16*)alloc(BH*2);
  u16*  ht0   =(u16*)alloc(BH*2);
  u16*  ht1   =(u16*)alloc(BH*2);
  u16*  decb  =(u16*)alloc(BH*2);
  float* wtf  =(float*)alloc(BH*4);
  float* whf  =(float*)alloc(BH*4);
  float* labf =(float*)alloc((size_t)Bsz*4);
  float* scf  =(float*)alloc((size_t)Bsz*Lenc*4);
  // cooperative scan buffers
  u16*  heA  =(u16*)alloc(BH*2);
  u16*  heB  =(u16*)alloc(BH*2);
  u16*  ceG  =(u16*)alloc(BH*2);
  u16*  spreG=(u16*)alloc(BH*2);
  float* scoreG=(float*)alloc(BH*4);
  u16*  xmodG=(u16*)alloc(BH*2);
  u16*  hmA  =(u16*)alloc(BH*2);
  u16*  hmB  =(u16*)alloc(BH*2);
  unsigned* barp=(unsigned*)alloc(256);

  hipMemsetAsync(barp, 0, 256, stream);   // reset grid-barrier counter each call

  dim3 cvtg(512), cvtb(256);
  k_cvt<<<cvtg,cvtb,0,stream>>>(f_Wih_sp ,wspih ,G4*Hd);
  k_cvt<<<cvtg,cvtb,0,stream>>>(f_Whh_sp ,wsphh ,G4*Hd);
  k_cvt<<<cvtg,cvtb,0,stream>>>(f_Whh_tg ,wtghh ,G4*Hd);
  k_cvt<<<cvtg,cvtb,0,stream>>>(f_Wih_mid,wmidih,G4*Hd);
  k_cvt<<<cvtg,cvtb,0,stream>>>(f_Whh_mid,wmidhh,G4*Hd);
  k_cvt<<<cvtg,cvtb,0,stream>>>(f_We_w   ,web   ,Hd*1024);
  k_cvt<<<cvtg,cvtb,0,stream>>>(f_Wt_w   ,wtb   ,Hd*1024);
  k_cvt<<<cvtg,cvtb,0,stream>>>(f_Wh_w   ,whb   ,Hd*1024);
  k_cvt<<<cvtg,cvtb,0,stream>>>(f_Vd_w   ,vdb   ,Hd*Hd);
  k_cvt<<<cvtg,cvtb,0,stream>>>(f_Wx_w   ,wxb   ,Hd*Hd);
  k_cvt<<<cvtg,cvtb,0,stream>>>(f_Wi_w   ,wib   ,Hd*Hd);
  k_cvt<<<dim3(1024),cvtb,0,stream>>>(f_inp, inpb, Bsz*Lenc*Din);
  k_cvt_tg<<<cvtg,cvtb,0,stream>>>(f_Wih_tg, wtgih, c0f);
  k_init<<<dim3(1),dim3(256),0,stream>>>(f_label, labf);
  k_wi<<<dim3(384,16),dim3(64),0,stream>>>(inpb, wib, f_Wi_b, wiseq);

  dim3 g816(8,16), b128(128);
  u16 *htR=ht0, *htW=ht1;
  for(int t=0;t<Look;t++){
    int t0 = (t==0)?1:0;
    k_tg<<<g816,b128,0,stream>>>(decb, htR, wtgih, wtghh, c0f, f_bih_tg, f_bhh_tg,
                                 labf, ctf, ctb, htW, t0);
    k_target<<<dim3(Bsz),dim3(64),0,stream>>>(htW, f_reg_w, f_reg_b, outp, labf, t);
    k_dual<<<g816,b128,0,stream>>>(htW, ctb, wtb, wtf);
    k_dual<<<g816,b128,0,stream>>>(htW, ctb, whb, whf);

    k_coop<<<dim3(256),dim3(512),0,stream>>>(
        f_inp, wiseq, wtf, web, vdb, f_Vd_b,
        wspih, wsphh, f_bih_sp, f_bhh_sp,
        wmidih, wmidhh, f_bih_mid, f_bhh_mid,
        heA, heB, ceG, spreG, scoreG, xmodG, hmA, hmB,
        mid2b, barp);

    k_scgemm<<<dim3(384,16),b128,0,stream>>>(mid2b, wxb, f_Wx_b, whf, ttb);
    k_scred<<<dim3(Lenc*Bsz),dim3(64),0,stream>>>(ttb, f_V_w, f_V_b, scf);
    k_dec<<<dim3(Bsz),dim3(256),0,stream>>>(scf, mid2b, decb);

    u16* tmp=htR; htR=htW; htW=tmp;
  }
}

// Round 8
// 46375.586 us; speedup vs baseline: 3.6361x; 3.6361x over previous
//
#include <hip/hip_runtime.h>
#include <math.h>

// Problem constants
#define Bsz   256
#define Hd    512
#define Din   512
#define Lenc  48
#define Look  10
#define G4    2048     // 4*H
#define LabStride 58   // LENC + LDEC
#define StartIdx  48   // LDEC + LENC - LOOK

typedef unsigned short u16;
using bfrag = __attribute__((ext_vector_type(8))) short;   // 8 bf16 (4 VGPRs)
using f32x4 = __attribute__((ext_vector_type(4))) float;   // 4 fp32 acc

#define MFMA16(a,b,c) __builtin_amdgcn_mfma_f32_16x16x32_bf16((a),(b),(c),0,0,0)

__device__ __forceinline__ u16 f2bf(float f){
  unsigned u = __float_as_uint(f);
  u += 0x7FFFu + ((u>>16)&1u);               // RNE
  return (u16)(u>>16);
}
__device__ __forceinline__ float bf2f(u16 h){ return __uint_as_float(((unsigned)h)<<16); }
__device__ __forceinline__ float sigm(float x){ return 1.f/(1.f+__expf(-x)); }

// ---- 32x32 output tile per wave (M=32), K-loop of 16x16x32 MFMAs ----
// A: activations [m][k] row-major (lda), W: weights [n][k] row-major (ldw) == B^T.
// Frag layout (m89/m91): A row = lane&15, k = 8*(lane>>4)+j ; same for W (row->n).
// acc[4] = [mi*2+ni], D: col(n)=lane&15, row(m)=4*(lane>>4)+reg.
template<int K>
__device__ __forceinline__ void mm32(const u16* __restrict__ A, int lda,
                                     const u16* __restrict__ W, int ldw,
                                     f32x4* acc, int lane){
  const int rr = lane & 15, ko = (lane>>4)<<3;
  const u16* a0 = A + (size_t)rr*lda + ko;
  const u16* a1 = a0 + 16*(size_t)lda;
  const u16* w0 = W + (size_t)rr*ldw + ko;
  const u16* w1 = w0 + 16*(size_t)ldw;
#pragma unroll
  for(int k=0;k<K;k+=32){
    bfrag av0 = *(const bfrag*)(a0+k);
    bfrag av1 = *(const bfrag*)(a1+k);
    bfrag wv0 = *(const bfrag*)(w0+k);
    bfrag wv1 = *(const bfrag*)(w1+k);
    acc[0] = MFMA16(av0,wv0,acc[0]);
    acc[1] = MFMA16(av0,wv1,acc[1]);
    acc[2] = MFMA16(av1,wv0,acc[2]);
    acc[3] = MFMA16(av1,wv1,acc[3]);
  }
}

// ---- M=16 x N=16*NT tile per wave, K=512. A global (lda=512), W in LDS (pitch LP).
// acc[n]: D row=4*(lane>>4)+j, col = n-tile col (lane&15).
template<int NT,int LP>
__device__ __forceinline__ void mmGL(const u16* __restrict__ A, const u16* W,
                                     f32x4* acc, int lane){
  const int rr=lane&15, ko=(lane>>4)<<3;
  const u16* a0=A+(size_t)rr*512+ko;
  const u16* w0=W+rr*LP+ko;
#pragma unroll
  for(int k=0;k<512;k+=32){
    bfrag av=*(const bfrag*)(a0+k);
#pragma unroll
    for(int n=0;n<NT;n++){
      bfrag wvv=*(const bfrag*)(w0+n*16*LP+k);
      acc[n]=MFMA16(av,wvv,acc[n]);
    }
  }
}

// ---- device-scope grid barrier (256 co-resident blocks, monotone counter) ----
// FIX vs r5: RELAXED polling (agent-scope atomics bypass L1/L2 to the coherence
// point, so values are fresh WITHOUT per-poll buffer_inv). Exactly one release
// fence before arrival and one acquire fence after target, by thread 0 only.
__device__ __forceinline__ void gbar(unsigned* bar){
  __syncthreads();
  if(threadIdx.x==0){
    __threadfence();   // release: write back this CU/XCD's dirty lines
    unsigned old=__hip_atomic_fetch_add(bar,1u,__ATOMIC_RELAXED,__HIP_MEMORY_SCOPE_AGENT);
    unsigned tgt=(old & ~255u)+256u;
    while(__hip_atomic_load(bar,__ATOMIC_RELAXED,__HIP_MEMORY_SCOPE_AGENT)<tgt)
      __builtin_amdgcn_s_sleep(2);
    __threadfence();   // acquire: invalidate so we observe other XCDs' stores
  }
  __syncthreads();
}

// ---------------- setup kernels ----------------
__global__ void k_cvt(const float* __restrict__ s, u16* __restrict__ d, int n){
  for(int i=blockIdx.x*blockDim.x+threadIdx.x; i<n; i+=gridDim.x*blockDim.x) d[i]=f2bf(s[i]);
}

// Wih_tg is (2048 x 513): col0 -> c0 (fp32), cols 1..512 -> packed bf16
__global__ void k_cvt_tg(const float* __restrict__ s, u16* __restrict__ d, float* __restrict__ c0){
  int stride=gridDim.x*blockDim.x;
  for(int i=blockIdx.x*blockDim.x+threadIdx.x; i<G4*Hd; i+=stride){
    int n=i>>9, k=i&511;
    d[i]=f2bf(s[n*513+1+k]);
  }
  for(int n=blockIdx.x*blockDim.x+threadIdx.x; n<G4; n+=stride) c0[n]=s[n*513];
}

__global__ void k_init(const float* __restrict__ label, float* __restrict__ lab){
  int b=threadIdx.x;
  if(b<Bsz) lab[b]=label[b*LabStride+StartIdx];
}

// wi_seq[l][b][h] = input[b][l][:] . Wi_w[h][:] + Wi_b[h]
__global__ __launch_bounds__(64) void k_wi(const u16* __restrict__ inpb, const u16* __restrict__ Wi,
                     const float* __restrict__ Wib, float* __restrict__ wi_seq){
  int lane=threadIdx.x;
  int r0=blockIdx.x*32, h0=blockIdx.y*32;
  f32x4 acc[4]={};
  mm32<Din>(inpb+(size_t)r0*Din, Din, Wi+(size_t)h0*Din, Din, acc, lane);
  int cr=(lane>>4)*4, cc=lane&15;
  for(int mi=0;mi<2;mi++)for(int ni=0;ni<2;ni++){
    int h=h0+ni*16+cc; float bias=Wib[h];
    f32x4 a=acc[mi*2+ni];
    for(int j=0;j<4;j++){
      int g=r0+mi*16+cr+j;
      int b=g/Lenc, l=g-b*Lenc;
      wi_seq[((size_t)l*Bsz+b)*Hd + h] = a[j]+bias;
    }
  }
}

// C = A1 @ W[:, :512]^T + A2 @ W[:, 512:]^T   (fp32 out; wt and wh)
__global__ __launch_bounds__(128) void k_dual(const u16* __restrict__ A1, const u16* __restrict__ A2,
      const u16* __restrict__ W, float* __restrict__ C){
  int lane=threadIdx.x&63, wid=threadIdx.x>>6;
  int b0=blockIdx.x*32, h0=blockIdx.y*32;
  f32x4 acc[4]={};
  if(wid==0) mm32<Hd>(A1+(size_t)b0*Hd, Hd, W+(size_t)h0*1024,     1024, acc, lane);
  else       mm32<Hd>(A2+(size_t)b0*Hd, Hd, W+(size_t)h0*1024+512, 1024, acc, lane);
  __shared__ f32x4 red[4*64];
  if(wid==1){ for(int i=0;i<4;i++) red[i*64+lane]=acc[i]; }
  __syncthreads();
  if(wid!=0) return;
  for(int i=0;i<4;i++) acc[i]+=red[i*64+lane];
  int cr=(lane>>4)*4, cc=lane&15;
  for(int mi=0;mi<2;mi++)for(int ni=0;ni<2;ni++){
    int h=h0+ni*16+cc;
    f32x4 a=acc[mi*2+ni];
    for(int j=0;j<4;j++){
      int b=b0+mi*16+cr+j;
      C[(size_t)b*Hd+h]=a[j];
    }
  }
}

// ============ cooperative weights-stationary scan (one launch per outer step) ============
// 256 blocks x 512 thr (1/CU co-resident). Roles by bid>>6:
//  R0 (0-63):   spre. LDS: We slice [16 cols][1032] (he|ce halves).
//  R1 (64-127): score + softmax/xmod. LDS: Vd slice [16][520].
//  R2 (128-191): sp gates+cell. LDS: Wih_sp/Whh_sp gate-major [64][520] x2. c_sp in regs.
//  R3 (192-255): mid gates+cell (runs concurrent with next spre). c_mid in regs.
// Per block: cg=(bid&63)>>1 (col group of 16), mh=bid&1 (batch half of 128 rows).
__global__ __launch_bounds__(512,1) void k_coop(
    const float* __restrict__ finp, const float* __restrict__ wiseq,
    const float* __restrict__ wtf,
    const u16* __restrict__ web, const u16* __restrict__ vdb, const float* __restrict__ vd_b,
    const u16* __restrict__ wspih, const u16* __restrict__ wsphh,
    const float* __restrict__ bih_sp, const float* __restrict__ bhh_sp,
    const u16* __restrict__ wmidih, const u16* __restrict__ wmidhh,
    const float* __restrict__ bih_mid, const float* __restrict__ bhh_mid,
    u16* __restrict__ heA, u16* __restrict__ heB, u16* __restrict__ ceG,
    u16* __restrict__ spreG, float* __restrict__ scoreG, u16* __restrict__ xmodG,
    u16* __restrict__ hmA, u16* __restrict__ hmB,
    u16* __restrict__ mid2b, unsigned* bar)
{
  __shared__ __align__(16) u16 LB[66560];   // 133 KB
  __shared__ float sred[16];
  const int tid=threadIdx.x, lane=tid&63, wv=tid>>6;
  const int bid=blockIdx.x;
  const int role=bid>>6;
  const int q=bid&63, cg=q>>1, mh=q&1;
  const int r0 = mh*128 + wv*16;            // wave's 16-row M tile
  const int col = cg*16 + (lane&15);        // this thread's output column
  const int rj0 = r0 + 4*(lane>>4);         // first of this thread's 4 rows

  // ---- prologue: stage weights into LDS (once per launch) ----
  if(role==0){
    for(int i=tid;i<16*128;i+=512){ int rr=i>>7, cc=(i&127)*8;
      *(bfrag*)(LB + rr*1032 + cc) = *(const bfrag*)(web + ((size_t)(cg*16+rr))*1024 + cc); }
  } else if(role==1){
    for(int i=tid;i<16*64;i+=512){ int rr=i>>6, cc=(i&63)*8;
      *(bfrag*)(LB + rr*520 + cc) = *(const bfrag*)(vdb + ((size_t)(cg*16+rr))*512 + cc); }
  } else {
    const u16* Wi = (role==2)? wspih : wmidih;
    const u16* Wh = (role==2)? wsphh : wmidhh;
    for(int i=tid;i<64*64;i+=512){ int rr=i>>6, cc=(i&63)*8;
      int gt=rr>>4, lr=rr&15;
      *(bfrag*)(LB + rr*520 + cc)         = *(const bfrag*)(Wi + ((size_t)(gt*512 + cg*16 + lr))*512 + cc);
      *(bfrag*)(LB + 33280 + rr*520 + cc) = *(const bfrag*)(Wh + ((size_t)(gt*512 + cg*16 + lr))*512 + cc);
    }
  }
  // zero state arrays (256KB each = 65536 u32; 256 blocks x 256 u32)
  if(tid<256){
    ((unsigned*)heA)[(size_t)bid*256+tid]=0;
    ((unsigned*)heB)[(size_t)bid*256+tid]=0;
    ((unsigned*)ceG)[(size_t)bid*256+tid]=0;
    ((unsigned*)hmA)[(size_t)bid*256+tid]=0;
    ((unsigned*)hmB)[(size_t)bid*256+tid]=0;
  }
  // per-role constants
  float wt_r[4]={0,0,0,0}; float bi0=0,bi1=0,bi2=0,bi3=0,vbias=0;
  if(role==0){ for(int j=0;j<4;j++) wt_r[j]=wtf[(size_t)(rj0+j)*Hd + col]; }
  if(role==1){ vbias=vd_b[col]; }
  if(role==2){ bi0=bih_sp[col]+bhh_sp[col];           bi1=bih_sp[512+col]+bhh_sp[512+col];
               bi2=bih_sp[1024+col]+bhh_sp[1024+col]; bi3=bih_sp[1536+col]+bhh_sp[1536+col]; }
  if(role==3){ bi0=bih_mid[col]+bhh_mid[col];           bi1=bih_mid[512+col]+bhh_mid[512+col];
               bi2=bih_mid[1024+col]+bhh_mid[1024+col]; bi3=bih_mid[1536+col]+bhh_mid[1536+col]; }
  f32x4 cst={0.f,0.f,0.f,0.f};

  auto P1=[&](int ll){   // spre(ll) = tanh(he@We1 + ce@We2 + wi + wt)
    const u16* heR = (ll&1)? heB : heA;
    f32x4 a={0.f,0.f,0.f,0.f};
    mmGL<1,1032>(heR+(size_t)r0*Hd, LB,     &a, lane);
    mmGL<1,1032>(ceG+(size_t)r0*Hd, LB+512, &a, lane);
#pragma unroll
    for(int j=0;j<4;j++)
      spreG[(size_t)(rj0+j)*Hd+col] =
        f2bf(tanhf(a[j] + wiseq[((size_t)ll*Bsz + rj0+j)*Hd + col] + wt_r[j]));
  };

  gbar(bar);
  if(role==0) P1(0);
  gbar(bar);

  for(int l=0;l<Lenc;l++){
    const u16* heR = (l&1)? heB : heA;
    u16*       heW = (l&1)? heA : heB;
    const u16* hmR = (l&1)? hmB : hmA;
    u16*       hmW = (l&1)? hmA : hmB;

    if(role==1){  // P2: score slice
      f32x4 a={0.f,0.f,0.f,0.f};
      mmGL<1,520>(spreG+(size_t)r0*Hd, LB, &a, lane);
#pragma unroll
      for(int j=0;j<4;j++) scoreG[(size_t)(rj0+j)*Hd+col] = a[j]+vbias;
    }
    gbar(bar);

    if(role==1){  // P3: softmax rows [4q,4q+4) + xmod
      int row = 4*q + (tid>>7); int cid = tid&127;
      float sc[4], xv[4];
#pragma unroll
      for(int jj=0;jj<4;jj++){
        sc[jj]=scoreG[(size_t)row*Hd + cid+128*jj];
        xv[jj]=finp[((size_t)row*Lenc + l)*Din + cid+128*jj];
      }
      float m=fmaxf(fmaxf(sc[0],sc[1]),fmaxf(sc[2],sc[3]));
      for(int o=1;o<64;o<<=1) m=fmaxf(m,__shfl_xor(m,o));
      if(lane==0) sred[wv]=m;
      __syncthreads();
      m=fmaxf(sred[(tid>>7)*2], sred[(tid>>7)*2+1]);
      float e[4]; float s=0.f;
#pragma unroll
      for(int jj=0;jj<4;jj++){ e[jj]=__expf(sc[jj]-m); s+=e[jj]; }
      for(int o=1;o<64;o<<=1) s+=__shfl_xor(s,o);
      if(lane==0) sred[8+wv]=s;
      __syncthreads();
      s = sred[8+(tid>>7)*2] + sred[8+(tid>>7)*2+1];
      float inv=1.f/s;
#pragma unroll
      for(int jj=0;jj<4;jj++)
        xmodG[(size_t)row*Hd + cid+128*jj] = f2bf(xv[jj]*e[jj]*inv);
    }
    gbar(bar);

    if(role==2){  // P4: sp gates + cell -> heW, ceG
      f32x4 acc[4]={};
      mmGL<4,520>(xmodG+(size_t)r0*Hd, LB,       acc, lane);
      mmGL<4,520>(heR  +(size_t)r0*Hd, LB+33280, acc, lane);
#pragma unroll
      for(int j=0;j<4;j++){
        float ii=sigm(acc[0][j]+bi0), ff=sigm(acc[1][j]+bi1);
        float gg=tanhf(acc[2][j]+bi2), oo=sigm(acc[3][j]+bi3);
        float c2=ff*cst[j]+ii*gg; cst[j]=c2;
        heW[(size_t)(rj0+j)*Hd+col]=f2bf(oo*tanhf(c2));
        ceG[(size_t)(rj0+j)*Hd+col]=f2bf(c2);
      }
    }
    gbar(bar);

    if(role==0 && l<Lenc-1) P1(l+1);     // concurrent with P5
    if(role==3){  // P5: mid gates + cell -> hmW, mid2b[l]
      f32x4 acc[4]={};
      mmGL<4,520>(heW+(size_t)r0*Hd, LB,       acc, lane);   // x-input = he_l
      mmGL<4,520>(hmR+(size_t)r0*Hd, LB+33280, acc, lane);
#pragma unroll
      for(int j=0;j<4;j++){
        float ii=sigm(acc[0][j]+bi0), ff=sigm(acc[1][j]+bi1);
        float gg=tanhf(acc[2][j]+bi2), oo=sigm(acc[3][j]+bi3);
        float c2=ff*cst[j]+ii*gg; cst[j]=c2;
        u16 hb=f2bf(oo*tanhf(c2));
        hmW[(size_t)(rj0+j)*Hd+col]=hb;
        mid2b[((size_t)l*Bsz + rj0+j)*Hd + col]=hb;
      }
    }
    gbar(bar);
  }
}

// tg cell: x = [lab, dec_in] (col0 handled via c0 in epilogue)
__global__ __launch_bounds__(128) void k_tg(const u16* __restrict__ dec, const u16* __restrict__ ht,
    const u16* __restrict__ Wih, const u16* __restrict__ Whh,
    const float* __restrict__ c0, const float* __restrict__ bih, const float* __restrict__ bhh,
    const float* __restrict__ lab, float* __restrict__ cst, u16* __restrict__ cbf,
    u16* __restrict__ hout, int t0){
  int lane=threadIdx.x&63, wid=threadIdx.x>>6;
  int b0=blockIdx.x*32, h0=blockIdx.y*32;
  f32x4 acc[4][4]={};
  if(!t0){
    if(wid==0){ for(int g=0;g<4;g++) mm32<Hd>(dec+(size_t)b0*Hd, Hd, Wih+((size_t)g*Hd+h0)*Hd, Hd, acc[g], lane); }
    else      { for(int g=0;g<4;g++) mm32<Hd>(ht +(size_t)b0*Hd, Hd, Whh+((size_t)g*Hd+h0)*Hd, Hd, acc[g], lane); }
  }
  __shared__ f32x4 red[16*64];
  if(wid==1){ for(int i=0;i<16;i++) red[i*64+lane]=acc[i>>2][i&3]; }
  __syncthreads();
  if(wid!=0) return;
  for(int i=0;i<16;i++) acc[i>>2][i&3]+=red[i*64+lane];
  int cr=(lane>>4)*4, cc=lane&15;
  for(int mi=0;mi<2;mi++)for(int ni=0;ni<2;ni++){
    int h=h0+ni*16+cc; int tq=mi*2+ni;
    float bi =bih[h]+bhh[h];
    float bff=bih[Hd+h]+bhh[Hd+h];
    float bg =bih[2*Hd+h]+bhh[2*Hd+h];
    float bo =bih[3*Hd+h]+bhh[3*Hd+h];
    float ci=c0[h], cf=c0[Hd+h], cg2=c0[2*Hd+h], co=c0[3*Hd+h];
    for(int j=0;j<4;j++){
      int b=b0+mi*16+cr+j;
      size_t ix=(size_t)b*Hd+h;
      float lb=lab[b];
      float ii=sigm(acc[0][tq][j]+bi +lb*ci);
      float ff=sigm(acc[1][tq][j]+bff+lb*cf);
      float gg=tanhf(acc[2][tq][j]+bg +lb*cg2);
      float oo=sigm(acc[3][tq][j]+bo +lb*co);
      float cold=t0?0.f:cst[ix];
      float c2=ff*cold+ii*gg;
      float hv=oo*tanhf(c2);
      cst[ix]=c2; cbf[ix]=f2bf(c2); hout[ix]=f2bf(hv);
    }
  }
}

// target = ht @ reg_w^T + reg_b ; out[b*Look+t] and lab update
__global__ __launch_bounds__(64) void k_target(const u16* __restrict__ ht, const float* __restrict__ regw,
     const float* __restrict__ regb, float* __restrict__ outp, float* __restrict__ lab, int t){
  int b=blockIdx.x, lane=threadIdx.x;
  bfrag v=*(const bfrag*)(ht+(size_t)b*Hd+lane*8);
  const float* w=regw+lane*8;
  float a=0;
  for(int j=0;j<8;j++) a+=bf2f((u16)v[j])*w[j];
  for(int o=1;o<64;o<<=1) a+=__shfl_xor(a,o);
  if(lane==0){ float val=a+regb[0]; outp[b*Look+t]=val; lab[b]=val; }
}

// TT = tanh(mid2 @ Wx^T + wh[b] + Wx_b)
__global__ __launch_bounds__(128) void k_scgemm(const u16* __restrict__ mid2, const u16* __restrict__ Wx,
      const float* __restrict__ Wxb, const float* __restrict__ wh, u16* __restrict__ TT){
  int lane=threadIdx.x&63, wid=threadIdx.x>>6;
  int r0=blockIdx.x*32, h0=blockIdx.y*32;
  f32x4 acc[4]={};
  mm32<256>(mid2+(size_t)r0*Hd + wid*256, Hd, Wx+(size_t)h0*Hd + wid*256, Hd, acc, lane);
  __shared__ f32x4 red[4*64];
  if(wid==1){ for(int i=0;i<4;i++) red[i*64+lane]=acc[i]; }
  __syncthreads();
  if(wid!=0) return;
  for(int i=0;i<4;i++) acc[i]+=red[i*64+lane];
  int cr=(lane>>4)*4, cc=lane&15;
  for(int mi=0;mi<2;mi++)for(int ni=0;ni<2;ni++){
    int h=h0+ni*16+cc; float wb=Wxb[h];
    f32x4 a=acc[mi*2+ni];
    for(int j=0;j<4;j++){
      int row=r0+mi*16+cr+j;
      int b=row&255;
      TT[(size_t)row*Hd+h]=f2bf(tanhf(a[j]+wh[(size_t)b*Hd+h]+wb));
    }
  }
}

// sc[b][l] = TT[row] . V_w + V_b   (row = l*B + b)
__global__ __launch_bounds__(64) void k_scred(const u16* __restrict__ TT, const float* __restrict__ Vw,
      const float* __restrict__ Vb, float* __restrict__ sc){
  int row=blockIdx.x, lane=threadIdx.x;
  bfrag v=*(const bfrag*)(TT+(size_t)row*Hd+lane*8);
  const float* w=Vw+lane*8;
  float a=0;
  for(int j=0;j<8;j++) a+=bf2f((u16)v[j])*w[j];
  for(int o=1;o<64;o<<=1) a+=__shfl_xor(a,o);
  if(lane==0){ int l=row>>8, b=row&255; sc[b*Lenc+l]=a+Vb[0]; }
}

// dec_in[b][h] = sum_l sc[b][l] * mid2[l][b][h]
__global__ __launch_bounds__(256) void k_dec(const float* __restrict__ sc, const u16* __restrict__ mid2,
      u16* __restrict__ dec){
  __shared__ float s[Lenc];
  int b=blockIdx.x, tid=threadIdx.x;
  if(tid<Lenc) s[tid]=sc[b*Lenc+tid];
  __syncthreads();
  for(int h=tid; h<Hd; h+=256){
    float a=0;
    for(int l=0;l<Lenc;l++) a+=s[l]*bf2f(mid2[((size_t)l*Bsz+b)*Hd+h]);
    dec[(size_t)b*Hd+h]=f2bf(a);
  }
}

// ---------------- host ----------------
extern "C" void kernel_launch(void* const* d_in, const int* in_sizes, int n_in,
                              void* d_out, int out_size, void* d_ws, size_t ws_size,
                              hipStream_t stream){
  const float* f_inp    =(const float*)d_in[0];
  const float* f_label  =(const float*)d_in[1];
  const float* f_Wih_sp =(const float*)d_in[2];
  const float* f_Whh_sp =(const float*)d_in[3];
  const float* f_bih_sp =(const float*)d_in[4];
  const float* f_bhh_sp =(const float*)d_in[5];
  const float* f_Wih_tg =(const float*)d_in[6];
  const float* f_Whh_tg =(const float*)d_in[7];
  const float* f_bih_tg =(const float*)d_in[8];
  const float* f_bhh_tg =(const float*)d_in[9];
  const float* f_Wih_mid=(const float*)d_in[10];
  const float* f_Whh_mid=(const float*)d_in[11];
  const float* f_bih_mid=(const float*)d_in[12];
  const float* f_bhh_mid=(const float*)d_in[13];
  const float* f_Wi_w   =(const float*)d_in[14];
  const float* f_Wi_b   =(const float*)d_in[15];
  const float* f_We_w   =(const float*)d_in[16];
  const float* f_Wt_w   =(const float*)d_in[17];
  const float* f_Vd_w   =(const float*)d_in[18];
  const float* f_Vd_b   =(const float*)d_in[19];
  const float* f_Wx_w   =(const float*)d_in[20];
  const float* f_Wx_b   =(const float*)d_in[21];
  const float* f_Wh_w   =(const float*)d_in[22];
  const float* f_V_w    =(const float*)d_in[23];
  const float* f_V_b    =(const float*)d_in[24];
  const float* f_reg_w  =(const float*)d_in[25];
  const float* f_reg_b  =(const float*)d_in[26];
  float* outp=(float*)d_out;

  char* basep=(char*)d_ws; size_t off=0;
  auto alloc=[&](size_t bytes)->void*{ void* r=basep+off; off+=(bytes+255)&~((size_t)255); return r; };

  const size_t BH=(size_t)Bsz*Hd;
  u16*  wspih =(u16*)alloc((size_t)G4*Hd*2);
  u16*  wsphh =(u16*)alloc((size_t)G4*Hd*2);
  u16*  wtgih =(u16*)alloc((size_t)G4*Hd*2);
  u16*  wtghh =(u16*)alloc((size_t)G4*Hd*2);
  u16*  wmidih=(u16*)alloc((size_t)G4*Hd*2);
  u16*  wmidhh=(u16*)alloc((size_t)G4*Hd*2);
  u16*  web   =(u16*)alloc((size_t)Hd*1024*2);
  u16*  wtb   =(u16*)alloc((size_t)Hd*1024*2);
  u16*  whb   =(u16*)alloc((size_t)Hd*1024*2);
  u16*  vdb   =(u16*)alloc((size_t)Hd*Hd*2);
  u16*  wxb   =(u16*)alloc((size_t)Hd*Hd*2);
  u16*  wib   =(u16*)alloc((size_t)Hd*Hd*2);
  u16*  inpb  =(u16*)alloc((size_t)Bsz*Lenc*Din*2);
  float* c0f  =(float*)alloc((size_t)G4*4);
  float* wiseq=(float*)alloc((size_t)Lenc*BH*4);
  u16*  mid2b =(u16*)alloc((size_t)Lenc*BH*2);
  u16*  ttb   =(u16*)alloc((size_t)Lenc*BH*2);
  float* ctf  =(float*)alloc(BH*4);
  u16*  ctb   =(u16*)alloc(BH*2);
  u16*  ht0   =(u16*)alloc(BH*2);
  u16*  ht1   =(u16*)alloc(BH*2);
  u16*  decb  =(u16*)alloc(BH*2);
  float* wtf  =(float*)alloc(BH*4);
  float* whf  =(float*)alloc(BH*4);
  float* labf =(float*)alloc((size_t)Bsz*4);
  float* scf  =(float*)alloc((size_t)Bsz*Lenc*4);
  // cooperative scan buffers
  u16*  heA  =(u16*)alloc(BH*2);
  u16*  heB  =(u16*)alloc(BH*2);
  u16*  ceG  =(u16*)alloc(BH*2);
  u16*  spreG=(u16*)alloc(BH*2);
  float* scoreG=(float*)alloc(BH*4);
  u16*  xmodG=(u16*)alloc(BH*2);
  u16*  hmA  =(u16*)alloc(BH*2);
  u16*  hmB  =(u16*)alloc(BH*2);
  unsigned* barp=(unsigned*)alloc(256);

  hipMemsetAsync(barp, 0, 256, stream);   // reset grid-barrier counter each call

  dim3 cvtg(512), cvtb(256);
  k_cvt<<<cvtg,cvtb,0,stream>>>(f_Wih_sp ,wspih ,G4*Hd);
  k_cvt<<<cvtg,cvtb,0,stream>>>(f_Whh_sp ,wsphh ,G4*Hd);
  k_cvt<<<cvtg,cvtb,0,stream>>>(f_Whh_tg ,wtghh ,G4*Hd);
  k_cvt<<<cvtg,cvtb,0,stream>>>(f_Wih_mid,wmidih,G4*Hd);
  k_cvt<<<cvtg,cvtb,0,stream>>>(f_Whh_mid,wmidhh,G4*Hd);
  k_cvt<<<cvtg,cvtb,0,stream>>>(f_We_w   ,web   ,Hd*1024);
  k_cvt<<<cvtg,cvtb,0,stream>>>(f_Wt_w   ,wtb   ,Hd*1024);
  k_cvt<<<cvtg,cvtb,0,stream>>>(f_Wh_w   ,whb   ,Hd*1024);
  k_cvt<<<cvtg,cvtb,0,stream>>>(f_Vd_w   ,vdb   ,Hd*Hd);
  k_cvt<<<cvtg,cvtb,0,stream>>>(f_Wx_w   ,wxb   ,Hd*Hd);
  k_cvt<<<cvtg,cvtb,0,stream>>>(f_Wi_w   ,wib   ,Hd*Hd);
  k_cvt<<<dim3(1024),cvtb,0,stream>>>(f_inp, inpb, Bsz*Lenc*Din);
  k_cvt_tg<<<cvtg,cvtb,0,stream>>>(f_Wih_tg, wtgih, c0f);
  k_init<<<dim3(1),dim3(256),0,stream>>>(f_label, labf);
  k_wi<<<dim3(384,16),dim3(64),0,stream>>>(inpb, wib, f_Wi_b, wiseq);

  dim3 g816(8,16), b128(128);
  u16 *htR=ht0, *htW=ht1;
  for(int t=0;t<Look;t++){
    int t0 = (t==0)?1:0;
    k_tg<<<g816,b128,0,stream>>>(decb, htR, wtgih, wtghh, c0f, f_bih_tg, f_bhh_tg,
                                 labf, ctf, ctb, htW, t0);
    k_target<<<dim3(Bsz),dim3(64),0,stream>>>(htW, f_reg_w, f_reg_b, outp, labf, t);
    k_dual<<<g816,b128,0,stream>>>(htW, ctb, wtb, wtf);
    k_dual<<<g816,b128,0,stream>>>(htW, ctb, whb, whf);

    k_coop<<<dim3(256),dim3(512),0,stream>>>(
        f_inp, wiseq, wtf, web, vdb, f_Vd_b,
        wspih, wsphh, f_bih_sp, f_bhh_sp,
        wmidih, wmidhh, f_bih_mid, f_bhh_mid,
        heA, heB, ceG, spreG, scoreG, xmodG, hmA, hmB,
        mid2b, barp);

    k_scgemm<<<dim3(384,16),b128,0,stream>>>(mid2b, wxb, f_Wx_b, whf, ttb);
    k_scred<<<dim3(Lenc*Bsz),dim3(64),0,stream>>>(ttb, f_V_w, f_V_b, scf);
    k_dec<<<dim3(Bsz),dim3(256),0,stream>>>(scf, mid2b, decb);

    u16* tmp=htR; htR=htW; htW=tmp;
  }
}

// Round 10
// 31458.017 us; speedup vs baseline: 5.3603x; 1.4742x over previous
//
#include <hip/hip_runtime.h>
#include <math.h>

// Problem constants
#define Bsz   256
#define Hd    512
#define Din   512
#define Lenc  48
#define Look  10
#define G4    2048     // 4*H
#define LabStride 58   // LENC + LDEC
#define StartIdx  48   // LDEC + LENC - LOOK

typedef unsigned short u16;
using bfrag = __attribute__((ext_vector_type(8))) short;   // 8 bf16 (4 VGPRs)
using f32x4 = __attribute__((ext_vector_type(4))) float;   // 4 fp32 acc

#define MFMA16(a,b,c) __builtin_amdgcn_mfma_f32_16x16x32_bf16((a),(b),(c),0,0,0)

__device__ __forceinline__ u16 f2bf(float f){
  unsigned u = __float_as_uint(f);
  u += 0x7FFFu + ((u>>16)&1u);               // RNE
  return (u16)(u>>16);
}
__device__ __forceinline__ float bf2f(u16 h){ return __uint_as_float(((unsigned)h)<<16); }
__device__ __forceinline__ float sigm(float x){ return 1.f/(1.f+__expf(-x)); }

// ---- 32x32 output tile per wave (M=32), K-loop of 16x16x32 MFMAs ----
// A: activations [m][k] row-major (lda), W: weights [n][k] row-major (ldw) == B^T.
// Frag layout (m89/m91): A row = lane&15, k = 8*(lane>>4)+j ; same for W (row->n).
// acc[4] = [mi*2+ni], D: col(n)=lane&15, row(m)=4*(lane>>4)+reg.
template<int K>
__device__ __forceinline__ void mm32(const u16* __restrict__ A, int lda,
                                     const u16* __restrict__ W, int ldw,
                                     f32x4* acc, int lane){
  const int rr = lane & 15, ko = (lane>>4)<<3;
  const u16* a0 = A + (size_t)rr*lda + ko;
  const u16* a1 = a0 + 16*(size_t)lda;
  const u16* w0 = W + (size_t)rr*ldw + ko;
  const u16* w1 = w0 + 16*(size_t)ldw;
#pragma unroll
  for(int k=0;k<K;k+=32){
    bfrag av0 = *(const bfrag*)(a0+k);
    bfrag av1 = *(const bfrag*)(a1+k);
    bfrag wv0 = *(const bfrag*)(w0+k);
    bfrag wv1 = *(const bfrag*)(w1+k);
    acc[0] = MFMA16(av0,wv0,acc[0]);
    acc[1] = MFMA16(av0,wv1,acc[1]);
    acc[2] = MFMA16(av1,wv0,acc[2]);
    acc[3] = MFMA16(av1,wv1,acc[3]);
  }
}

// ---------------- setup kernels ----------------
__global__ void k_cvt(const float* __restrict__ s, u16* __restrict__ d, int n){
  for(int i=blockIdx.x*blockDim.x+threadIdx.x; i<n; i+=gridDim.x*blockDim.x) d[i]=f2bf(s[i]);
}

// Wih_tg is (2048 x 513): col0 -> c0 (fp32), cols 1..512 -> packed bf16
__global__ void k_cvt_tg(const float* __restrict__ s, u16* __restrict__ d, float* __restrict__ c0){
  int stride=gridDim.x*blockDim.x;
  for(int i=blockIdx.x*blockDim.x+threadIdx.x; i<G4*Hd; i+=stride){
    int n=i>>9, k=i&511;
    d[i]=f2bf(s[n*513+1+k]);
  }
  for(int n=blockIdx.x*blockDim.x+threadIdx.x; n<G4; n+=stride) c0[n]=s[n*513];
}

__global__ void k_init(const float* __restrict__ label, float* __restrict__ lab){
  int b=threadIdx.x;
  if(b<Bsz) lab[b]=label[b*LabStride+StartIdx];
}

// wi_seq[l][b][h] = input[b][l][:] . Wi_w[h][:] + Wi_b[h]
__global__ __launch_bounds__(64) void k_wi(const u16* __restrict__ inpb, const u16* __restrict__ Wi,
                     const float* __restrict__ Wib, float* __restrict__ wi_seq){
  int lane=threadIdx.x;
  int r0=blockIdx.x*32, h0=blockIdx.y*32;
  f32x4 acc[4]={};
  mm32<Din>(inpb+(size_t)r0*Din, Din, Wi+(size_t)h0*Din, Din, acc, lane);
  int cr=(lane>>4)*4, cc=lane&15;
  for(int mi=0;mi<2;mi++)for(int ni=0;ni<2;ni++){
    int h=h0+ni*16+cc; float bias=Wib[h];
    f32x4 a=acc[mi*2+ni];
    for(int j=0;j<4;j++){
      int g=r0+mi*16+cr+j;
      int b=g/Lenc, l=g-b*Lenc;
      wi_seq[((size_t)l*Bsz+b)*Hd + h] = a[j]+bias;
    }
  }
}

// Both outer-step dual GEMMs in one launch: z=0: wt = [ht,ct]@Wt^T ; z=1: wh = [ht,ct]@Wh^T
__global__ __launch_bounds__(128) void k_dual2(const u16* __restrict__ A1, const u16* __restrict__ A2,
      const u16* __restrict__ W0, const u16* __restrict__ W1,
      float* __restrict__ C0, float* __restrict__ C1){
  const u16* W = blockIdx.z ? W1 : W0;
  float*     C = blockIdx.z ? C1 : C0;
  int lane=threadIdx.x&63, wid=threadIdx.x>>6;
  int b0=blockIdx.x*32, h0=blockIdx.y*32;
  f32x4 acc[4]={};
  if(wid==0) mm32<Hd>(A1+(size_t)b0*Hd, Hd, W+(size_t)h0*1024,     1024, acc, lane);
  else       mm32<Hd>(A2+(size_t)b0*Hd, Hd, W+(size_t)h0*1024+512, 1024, acc, lane);
  __shared__ f32x4 red[4*64];
  if(wid==1){ for(int i=0;i<4;i++) red[i*64+lane]=acc[i]; }
  __syncthreads();
  if(wid!=0) return;
  for(int i=0;i<4;i++) acc[i]+=red[i*64+lane];
  int cr=(lane>>4)*4, cc=lane&15;
  for(int mi=0;mi<2;mi++)for(int ni=0;ni<2;ni++){
    int h=h0+ni*16+cc;
    f32x4 a=acc[mi*2+ni];
    for(int j=0;j<4;j++){
      int b=b0+mi*16+cr+j;
      C[(size_t)b*Hd+h]=a[j];
    }
  }
}

// ---- fused: z=0 -> spre_l ; z=1 -> mid cell for step l-1 (independent work) ----
// z0: spre = tanh([he,ce]@We^T + wi_l + wt)  (2 waves K-split over he|ce)
// z1: mid gates = mx@Wih^T + mh@Whh^T, cell update, out mid2[l-1]
__global__ __launch_bounds__(128) void k_spre_mid(
      const u16* __restrict__ he, const u16* __restrict__ ce, const u16* __restrict__ web,
      const float* __restrict__ wi_l, const float* __restrict__ wt, u16* __restrict__ spre, int zhc,
      const u16* __restrict__ mx, const u16* __restrict__ mh,
      const u16* __restrict__ wmih, const u16* __restrict__ wmhh,
      const float* __restrict__ bihm, const float* __restrict__ bhhm,
      float* __restrict__ cmid, u16* __restrict__ mout, int men, int ml0){
  __shared__ f32x4 red[16*64];
  int lane=threadIdx.x&63, wid=threadIdx.x>>6;
  int b0=blockIdx.x*32, h0=blockIdx.y*32;
  int cr=(lane>>4)*4, cc=lane&15;

  if(blockIdx.z==0){
    f32x4 acc[4]={};
    if(!zhc){
      if(wid==0) mm32<Hd>(he+(size_t)b0*Hd, Hd, web+(size_t)h0*1024,     1024, acc, lane);
      else       mm32<Hd>(ce+(size_t)b0*Hd, Hd, web+(size_t)h0*1024+512, 1024, acc, lane);
    }
    if(wid==1){ for(int i=0;i<4;i++) red[i*64+lane]=acc[i]; }
    __syncthreads();
    if(wid!=0) return;
    for(int i=0;i<4;i++) acc[i]+=red[i*64+lane];
    for(int mi=0;mi<2;mi++)for(int ni=0;ni<2;ni++){
      int h=h0+ni*16+cc;
      f32x4 a=acc[mi*2+ni];
      for(int j=0;j<4;j++){
        int b=b0+mi*16+cr+j;
        size_t ix=(size_t)b*Hd+h;
        spre[ix]=f2bf(tanhf(a[j]+wi_l[ix]+wt[ix]));
      }
    }
  } else {
    if(!men) return;
    f32x4 acc[4][4]={};
    if(wid==0){
      for(int g=0;g<4;g++) mm32<Hd>(mx+(size_t)b0*Hd, Hd, wmih+((size_t)g*Hd+h0)*Hd, Hd, acc[g], lane);
    } else if(!ml0){
      for(int g=0;g<4;g++) mm32<Hd>(mh+(size_t)b0*Hd, Hd, wmhh+((size_t)g*Hd+h0)*Hd, Hd, acc[g], lane);
    }
    if(wid==1){ for(int i=0;i<16;i++) red[i*64+lane]=acc[i>>2][i&3]; }
    __syncthreads();
    if(wid!=0) return;
    for(int i=0;i<16;i++) acc[i>>2][i&3]+=red[i*64+lane];
    for(int mi=0;mi<2;mi++)for(int ni=0;ni<2;ni++){
      int h=h0+ni*16+cc; int tq=mi*2+ni;
      float bi =bihm[h]+bhhm[h];
      float bff=bihm[Hd+h]+bhhm[Hd+h];
      float bg =bihm[2*Hd+h]+bhhm[2*Hd+h];
      float bo =bihm[3*Hd+h]+bhhm[3*Hd+h];
      for(int j=0;j<4;j++){
        int b=b0+mi*16+cr+j;
        size_t ix=(size_t)b*Hd+h;
        float ii=sigm(acc[0][tq][j]+bi);
        float ff=sigm(acc[1][tq][j]+bff);
        float gg=tanhf(acc[2][tq][j]+bg);
        float oo=sigm(acc[3][tq][j]+bo);
        float cold=ml0?0.f:cmid[ix];
        float c2=ff*cold+ii*gg;
        cmid[ix]=c2;
        mout[ix]=f2bf(oo*tanhf(c2));
      }
    }
  }
}

// score = spre @ Vd^T + Vd_b  (fp32 out; K=512 split across 2 waves)
__global__ __launch_bounds__(128) void k_sgemm(const u16* __restrict__ spre, const u16* __restrict__ Vd,
      const float* __restrict__ Vdb, float* __restrict__ score){
  int lane=threadIdx.x&63, wid=threadIdx.x>>6;
  int b0=blockIdx.x*32, h0=blockIdx.y*32;
  f32x4 acc[4]={};
  mm32<256>(spre+(size_t)b0*Hd + wid*256, Hd, Vd+(size_t)h0*Hd + wid*256, Hd, acc, lane);
  __shared__ f32x4 red[4*64];
  if(wid==1){ for(int i=0;i<4;i++) red[i*64+lane]=acc[i]; }
  __syncthreads();
  if(wid!=0) return;
  for(int i=0;i<4;i++) acc[i]+=red[i*64+lane];
  int cr=(lane>>4)*4, cc=lane&15;
  for(int mi=0;mi<2;mi++)for(int ni=0;ni<2;ni++){
    int h=h0+ni*16+cc; float bias=Vdb[h];
    f32x4 a=acc[mi*2+ni];
    for(int j=0;j<4;j++){
      int b=b0+mi*16+cr+j;
      score[(size_t)b*Hd+h]=a[j]+bias;
    }
  }
}

// ---- fused softmax + sp gates + cell ----
// Block (b0,h0): softmax rows b0..b0+31 from fp32 score (block-local, 4 lanes/row),
// xmod -> LDS; then gates = xmod(LDS)@Wih^T + hprev@Whh^T; cell epilogue.
#define XP 520
__global__ __launch_bounds__(128) void k_cellF(const float* __restrict__ score,
     const float* __restrict__ finp, int l,
     const u16* __restrict__ hprev, const u16* __restrict__ Wih, const u16* __restrict__ Whh,
     const float* __restrict__ bih, const float* __restrict__ bhh,
     float* __restrict__ cst, u16* __restrict__ cbf, u16* __restrict__ hout, int l0){
  __shared__ __align__(16) u16 xm[32*XP];
  __shared__ f32x4 red[16*64];
  int tid=threadIdx.x, lane=tid&63, wid=tid>>6;
  int b0=blockIdx.x*32, h0=blockIdx.y*32;

  // --- softmax phase: row r = tid>>2, lanes (tid&3) cover 128 cols each ---
  {
    int r=tid>>2, q=tid&3;
    int b=b0+r;
    const float* srow = score + (size_t)b*Hd + q*128;
    const float* xrow = finp + ((size_t)b*Lenc + l)*Din + q*128;
    float m=-1e30f;
    for(int j=0;j<128;j+=4){
      float4 v=*(const float4*)(srow+j);
      m=fmaxf(m,fmaxf(fmaxf(v.x,v.y),fmaxf(v.z,v.w)));
    }
    m=fmaxf(m,__shfl_xor(m,1));
    m=fmaxf(m,__shfl_xor(m,2));
    float ssum=0.f;
    for(int j=0;j<128;j+=4){
      float4 v=*(const float4*)(srow+j);
      ssum+=__expf(v.x-m)+__expf(v.y-m)+__expf(v.z-m)+__expf(v.w-m);
    }
    ssum+=__shfl_xor(ssum,1);
    ssum+=__shfl_xor(ssum,2);
    float inv=1.f/ssum;
    for(int j=0;j<128;j+=4){
      float4 v=*(const float4*)(srow+j);
      float4 x=*(const float4*)(xrow+j);
      ushort4 o;
      o.x=f2bf(x.x*__expf(v.x-m)*inv);
      o.y=f2bf(x.y*__expf(v.y-m)*inv);
      o.z=f2bf(x.z*__expf(v.z-m)*inv);
      o.w=f2bf(x.w*__expf(v.w-m)*inv);
      *(ushort4*)(&xm[r*XP + q*128 + j]) = o;
    }
  }
  __syncthreads();

  // --- gates phase: wave0 x-part (LDS xmod), wave1 h-part (global hprev) ---
  f32x4 acc[4][4]={};
  if(wid==0){
    for(int g=0;g<4;g++) mm32<Hd>((const u16*)xm, XP, Wih+((size_t)g*Hd+h0)*Hd, Hd, acc[g], lane);
  } else if(!l0){
    for(int g=0;g<4;g++) mm32<Hd>(hprev+(size_t)b0*Hd, Hd, Whh+((size_t)g*Hd+h0)*Hd, Hd, acc[g], lane);
  }
  __syncthreads();   // xm reads done (wave0) before red reuse is fine; red distinct anyway
  if(wid==1){ for(int i=0;i<16;i++) red[i*64+lane]=acc[i>>2][i&3]; }
  __syncthreads();
  if(wid!=0) return;
  for(int i=0;i<16;i++) acc[i>>2][i&3]+=red[i*64+lane];
  int cr=(lane>>4)*4, cc=lane&15;
  for(int mi=0;mi<2;mi++)for(int ni=0;ni<2;ni++){
    int h=h0+ni*16+cc; int tq=mi*2+ni;
    float bi =bih[h]+bhh[h];
    float bff=bih[Hd+h]+bhh[Hd+h];
    float bg =bih[2*Hd+h]+bhh[2*Hd+h];
    float bo =bih[3*Hd+h]+bhh[3*Hd+h];
    for(int j=0;j<4;j++){
      int b=b0+mi*16+cr+j;
      size_t ix=(size_t)b*Hd+h;
      float ii=sigm(acc[0][tq][j]+bi);
      float ff=sigm(acc[1][tq][j]+bff);
      float gg=tanhf(acc[2][tq][j]+bg);
      float oo=sigm(acc[3][tq][j]+bo);
      float cold=l0?0.f:cst[ix];
      float c2=ff*cold+ii*gg;
      float hv=oo*tanhf(c2);
      cst[ix]=c2;
      cbf[ix]=f2bf(c2);
      hout[ix]=f2bf(hv);
    }
  }
}

// plain LSTM cell (kept for mid step 47): gates = A1@Wih^T + A2@Whh^T
__global__ __launch_bounds__(128) void k_cell(const u16* __restrict__ A1, const u16* __restrict__ A2,
     const u16* __restrict__ Wih, const u16* __restrict__ Whh,
     const float* __restrict__ bih, const float* __restrict__ bhh,
     float* __restrict__ cst, u16* __restrict__ cbf, u16* __restrict__ hout, int l0){
  int lane=threadIdx.x&63, wid=threadIdx.x>>6;
  int b0=blockIdx.x*32, h0=blockIdx.y*32;
  f32x4 acc[4][4]={};
  if(wid==0){
    for(int g=0;g<4;g++) mm32<Hd>(A1+(size_t)b0*Hd, Hd, Wih+((size_t)g*Hd+h0)*Hd, Hd, acc[g], lane);
  } else if(!l0){
    for(int g=0;g<4;g++) mm32<Hd>(A2+(size_t)b0*Hd, Hd, Whh+((size_t)g*Hd+h0)*Hd, Hd, acc[g], lane);
  }
  __shared__ f32x4 red[16*64];
  if(wid==1){ for(int i=0;i<16;i++) red[i*64+lane]=acc[i>>2][i&3]; }
  __syncthreads();
  if(wid!=0) return;
  for(int i=0;i<16;i++) acc[i>>2][i&3]+=red[i*64+lane];
  int cr=(lane>>4)*4, cc=lane&15;
  for(int mi=0;mi<2;mi++)for(int ni=0;ni<2;ni++){
    int h=h0+ni*16+cc; int tq=mi*2+ni;
    float bi =bih[h]+bhh[h];
    float bff=bih[Hd+h]+bhh[Hd+h];
    float bg =bih[2*Hd+h]+bhh[2*Hd+h];
    float bo =bih[3*Hd+h]+bhh[3*Hd+h];
    for(int j=0;j<4;j++){
      int b=b0+mi*16+cr+j;
      size_t ix=(size_t)b*Hd+h;
      float ii=sigm(acc[0][tq][j]+bi);
      float ff=sigm(acc[1][tq][j]+bff);
      float gg=tanhf(acc[2][tq][j]+bg);
      float oo=sigm(acc[3][tq][j]+bo);
      float cold=l0?0.f:cst[ix];
      float c2=ff*cold+ii*gg;
      float hv=oo*tanhf(c2);
      cst[ix]=c2;
      if(cbf) cbf[ix]=f2bf(c2);
      hout[ix]=f2bf(hv);
    }
  }
}

// tg cell: x = [lab, dec_in] (col0 handled via c0 in epilogue)
__global__ __launch_bounds__(128) void k_tg(const u16* __restrict__ dec, const u16* __restrict__ ht,
    const u16* __restrict__ Wih, const u16* __restrict__ Whh,
    const float* __restrict__ c0, const float* __restrict__ bih, const float* __restrict__ bhh,
    const float* __restrict__ lab, float* __restrict__ cst, u16* __restrict__ cbf,
    u16* __restrict__ hout, int t0){
  int lane=threadIdx.x&63, wid=threadIdx.x>>6;
  int b0=blockIdx.x*32, h0=blockIdx.y*32;
  f32x4 acc[4][4]={};
  if(!t0){
    if(wid==0){ for(int g=0;g<4;g++) mm32<Hd>(dec+(size_t)b0*Hd, Hd, Wih+((size_t)g*Hd+h0)*Hd, Hd, acc[g], lane); }
    else      { for(int g=0;g<4;g++) mm32<Hd>(ht +(size_t)b0*Hd, Hd, Whh+((size_t)g*Hd+h0)*Hd, Hd, acc[g], lane); }
  }
  __shared__ f32x4 red[16*64];
  if(wid==1){ for(int i=0;i<16;i++) red[i*64+lane]=acc[i>>2][i&3]; }
  __syncthreads();
  if(wid!=0) return;
  for(int i=0;i<16;i++) acc[i>>2][i&3]+=red[i*64+lane];
  int cr=(lane>>4)*4, cc=lane&15;
  for(int mi=0;mi<2;mi++)for(int ni=0;ni<2;ni++){
    int h=h0+ni*16+cc; int tq=mi*2+ni;
    float bi =bih[h]+bhh[h];
    float bff=bih[Hd+h]+bhh[Hd+h];
    float bg =bih[2*Hd+h]+bhh[2*Hd+h];
    float bo =bih[3*Hd+h]+bhh[3*Hd+h];
    float ci=c0[h], cf=c0[Hd+h], cg2=c0[2*Hd+h], co=c0[3*Hd+h];
    for(int j=0;j<4;j++){
      int b=b0+mi*16+cr+j;
      size_t ix=(size_t)b*Hd+h;
      float lb=lab[b];
      float ii=sigm(acc[0][tq][j]+bi +lb*ci);
      float ff=sigm(acc[1][tq][j]+bff+lb*cf);
      float gg=tanhf(acc[2][tq][j]+bg +lb*cg2);
      float oo=sigm(acc[3][tq][j]+bo +lb*co);
      float cold=t0?0.f:cst[ix];
      float c2=ff*cold+ii*gg;
      float hv=oo*tanhf(c2);
      cst[ix]=c2; cbf[ix]=f2bf(c2); hout[ix]=f2bf(hv);
    }
  }
}

// target = ht @ reg_w^T + reg_b ; out[b*Look+t] and lab update
__global__ __launch_bounds__(64) void k_target(const u16* __restrict__ ht, const float* __restrict__ regw,
     const float* __restrict__ regb, float* __restrict__ outp, float* __restrict__ lab, int t){
  int b=blockIdx.x, lane=threadIdx.x;
  bfrag v=*(const bfrag*)(ht+(size_t)b*Hd+lane*8);
  const float* w=regw+lane*8;
  float a=0;
  for(int j=0;j<8;j++) a+=bf2f((u16)v[j])*w[j];
  for(int o=1;o<64;o<<=1) a+=__shfl_xor(a,o);
  if(lane==0){ float val=a+regb[0]; outp[b*Look+t]=val; lab[b]=val; }
}

// TT = tanh(mid2 @ Wx^T + wh[b] + Wx_b)
__global__ __launch_bounds__(128) void k_scgemm(const u16* __restrict__ mid2, const u16* __restrict__ Wx,
      const float* __restrict__ Wxb, const float* __restrict__ wh, u16* __restrict__ TT){
  int lane=threadIdx.x&63, wid=threadIdx.x>>6;
  int r0=blockIdx.x*32, h0=blockIdx.y*32;
  f32x4 acc[4]={};
  mm32<256>(mid2+(size_t)r0*Hd + wid*256, Hd, Wx+(size_t)h0*Hd + wid*256, Hd, acc, lane);
  __shared__ f32x4 red[4*64];
  if(wid==1){ for(int i=0;i<4;i++) red[i*64+lane]=acc[i]; }
  __syncthreads();
  if(wid!=0) return;
  for(int i=0;i<4;i++) acc[i]+=red[i*64+lane];
  int cr=(lane>>4)*4, cc=lane&15;
  for(int mi=0;mi<2;mi++)for(int ni=0;ni<2;ni++){
    int h=h0+ni*16+cc; float wb=Wxb[h];
    f32x4 a=acc[mi*2+ni];
    for(int j=0;j<4;j++){
      int row=r0+mi*16+cr+j;
      int b=row&255;
      TT[(size_t)row*Hd+h]=f2bf(tanhf(a[j]+wh[(size_t)b*Hd+h]+wb));
    }
  }
}

// sc[b][l] = TT[row] . V_w + V_b   (row = l*B + b)
__global__ __launch_bounds__(64) void k_scred(const u16* __restrict__ TT, const float* __restrict__ Vw,
      const float* __restrict__ Vb, float* __restrict__ sc){
  int row=blockIdx.x, lane=threadIdx.x;
  bfrag v=*(const bfrag*)(TT+(size_t)row*Hd+lane*8);
  const float* w=Vw+lane*8;
  float a=0;
  for(int j=0;j<8;j++) a+=bf2f((u16)v[j])*w[j];
  for(int o=1;o<64;o<<=1) a+=__shfl_xor(a,o);
  if(lane==0){ int l=row>>8, b=row&255; sc[b*Lenc+l]=a+Vb[0]; }
}

// dec_in[b][h] = sum_l sc[b][l] * mid2[l][b][h]
__global__ __launch_bounds__(256) void k_dec(const float* __restrict__ sc, const u16* __restrict__ mid2,
      u16* __restrict__ dec){
  __shared__ float s[Lenc];
  int b=blockIdx.x, tid=threadIdx.x;
  if(tid<Lenc) s[tid]=sc[b*Lenc+tid];
  __syncthreads();
  for(int h=tid; h<Hd; h+=256){
    float a=0;
    for(int l=0;l<Lenc;l++) a+=s[l]*bf2f(mid2[((size_t)l*Bsz+b)*Hd+h]);
    dec[(size_t)b*Hd+h]=f2bf(a);
  }
}

// ---------------- host ----------------
extern "C" void kernel_launch(void* const* d_in, const int* in_sizes, int n_in,
                              void* d_out, int out_size, void* d_ws, size_t ws_size,
                              hipStream_t stream){
  const float* f_inp    =(const float*)d_in[0];
  const float* f_label  =(const float*)d_in[1];
  const float* f_Wih_sp =(const float*)d_in[2];
  const float* f_Whh_sp =(const float*)d_in[3];
  const float* f_bih_sp =(const float*)d_in[4];
  const float* f_bhh_sp =(const float*)d_in[5];
  const float* f_Wih_tg =(const float*)d_in[6];
  const float* f_Whh_tg =(const float*)d_in[7];
  const float* f_bih_tg =(const float*)d_in[8];
  const float* f_bhh_tg =(const float*)d_in[9];
  const float* f_Wih_mid=(const float*)d_in[10];
  const float* f_Whh_mid=(const float*)d_in[11];
  const float* f_bih_mid=(const float*)d_in[12];
  const float* f_bhh_mid=(const float*)d_in[13];
  const float* f_Wi_w   =(const float*)d_in[14];
  const float* f_Wi_b   =(const float*)d_in[15];
  const float* f_We_w   =(const float*)d_in[16];
  const float* f_Wt_w   =(const float*)d_in[17];
  const float* f_Vd_w   =(const float*)d_in[18];
  const float* f_Vd_b   =(const float*)d_in[19];
  const float* f_Wx_w   =(const float*)d_in[20];
  const float* f_Wx_b   =(const float*)d_in[21];
  const float* f_Wh_w   =(const float*)d_in[22];
  const float* f_V_w    =(const float*)d_in[23];
  const float* f_V_b    =(const float*)d_in[24];
  const float* f_reg_w  =(const float*)d_in[25];
  const float* f_reg_b  =(const float*)d_in[26];
  float* outp=(float*)d_out;

  char* basep=(char*)d_ws; size_t off=0;
  auto alloc=[&](size_t bytes)->void*{ void* r=basep+off; off+=(bytes+255)&~((size_t)255); return r; };

  const size_t BH=(size_t)Bsz*Hd;
  u16*  wspih =(u16*)alloc((size_t)G4*Hd*2);
  u16*  wsphh =(u16*)alloc((size_t)G4*Hd*2);
  u16*  wtgih =(u16*)alloc((size_t)G4*Hd*2);
  u16*  wtghh =(u16*)alloc((size_t)G4*Hd*2);
  u16*  wmidih=(u16*)alloc((size_t)G4*Hd*2);
  u16*  wmidhh=(u16*)alloc((size_t)G4*Hd*2);
  u16*  web   =(u16*)alloc((size_t)Hd*1024*2);
  u16*  wtb   =(u16*)alloc((size_t)Hd*1024*2);
  u16*  whb   =(u16*)alloc((size_t)Hd*1024*2);
  u16*  vdb   =(u16*)alloc((size_t)Hd*Hd*2);
  u16*  wxb   =(u16*)alloc((size_t)Hd*Hd*2);
  u16*  wib   =(u16*)alloc((size_t)Hd*Hd*2);
  u16*  inpb  =(u16*)alloc((size_t)Bsz*Lenc*Din*2);
  float* c0f  =(float*)alloc((size_t)G4*4);
  float* wiseq=(float*)alloc((size_t)Lenc*BH*4);
  u16*  midb  =(u16*)alloc((size_t)Lenc*BH*2);
  u16*  mid2b =(u16*)alloc((size_t)Lenc*BH*2);
  u16*  ttb   =(u16*)alloc((size_t)Lenc*BH*2);
  u16*  spreb =(u16*)alloc(BH*2);
  float* scoref=(float*)alloc(BH*4);
  float* cef  =(float*)alloc(BH*4);
  u16*  ceb   =(u16*)alloc(BH*2);
  float* ctf  =(float*)alloc(BH*4);
  u16*  ctb   =(u16*)alloc(BH*2);
  float* cmidf=(float*)alloc(BH*4);
  u16*  ht0   =(u16*)alloc(BH*2);
  u16*  ht1   =(u16*)alloc(BH*2);
  u16*  decb  =(u16*)alloc(BH*2);
  float* wtf  =(float*)alloc(BH*4);
  float* whf  =(float*)alloc(BH*4);
  float* labf =(float*)alloc((size_t)Bsz*4);
  float* scf  =(float*)alloc((size_t)Bsz*Lenc*4);

  dim3 cvtg(512), cvtb(256);
  k_cvt<<<cvtg,cvtb,0,stream>>>(f_Wih_sp ,wspih ,G4*Hd);
  k_cvt<<<cvtg,cvtb,0,stream>>>(f_Whh_sp ,wsphh ,G4*Hd);
  k_cvt<<<cvtg,cvtb,0,stream>>>(f_Whh_tg ,wtghh ,G4*Hd);
  k_cvt<<<cvtg,cvtb,0,stream>>>(f_Wih_mid,wmidih,G4*Hd);
  k_cvt<<<cvtg,cvtb,0,stream>>>(f_Whh_mid,wmidhh,G4*Hd);
  k_cvt<<<cvtg,cvtb,0,stream>>>(f_We_w   ,web   ,Hd*1024);
  k_cvt<<<cvtg,cvtb,0,stream>>>(f_Wt_w   ,wtb   ,Hd*1024);
  k_cvt<<<cvtg,cvtb,0,stream>>>(f_Wh_w   ,whb   ,Hd*1024);
  k_cvt<<<cvtg,cvtb,0,stream>>>(f_Vd_w   ,vdb   ,Hd*Hd);
  k_cvt<<<cvtg,cvtb,0,stream>>>(f_Wx_w   ,wxb   ,Hd*Hd);
  k_cvt<<<cvtg,cvtb,0,stream>>>(f_Wi_w   ,wib   ,Hd*Hd);
  k_cvt<<<dim3(1024),cvtb,0,stream>>>(f_inp, inpb, Bsz*Lenc*Din);
  k_cvt_tg<<<cvtg,cvtb,0,stream>>>(f_Wih_tg, wtgih, c0f);
  k_init<<<dim3(1),dim3(256),0,stream>>>(f_label, labf);
  k_wi<<<dim3(384,16),dim3(64),0,stream>>>(inpb, wib, f_Wi_b, wiseq);

  dim3 g816(8,16), g816z2(8,16,2), b128(128);
  u16 *htR=ht0, *htW=ht1;
  for(int t=0;t<Look;t++){
    int t0 = (t==0)?1:0;
    k_tg<<<g816,b128,0,stream>>>(decb, htR, wtgih, wtghh, c0f, f_bih_tg, f_bhh_tg,
                                 labf, ctf, ctb, htW, t0);
    k_target<<<dim3(Bsz),dim3(64),0,stream>>>(htW, f_reg_w, f_reg_b, outp, labf, t);
    k_dual2<<<g816z2,b128,0,stream>>>(htW, ctb, wtb, whb, wtf, whf);

    for(int l=0;l<Lenc;l++){
      int l0=(l==0)?1:0;
      const u16* hprev = l0 ? midb : (midb + (size_t)(l-1)*BH);
      // z0: spre_l ; z1: mid cell for step l-1 (runs concurrently, independent data)
      const u16* mx = l0 ? midb  : (midb  + (size_t)(l-1)*BH);
      const u16* mh = (l<=1) ? mid2b : (mid2b + (size_t)(l-2)*BH);
      u16* mout = l0 ? mid2b : (mid2b + (size_t)(l-1)*BH);
      k_spre_mid<<<g816z2,b128,0,stream>>>(hprev, ceb, web, wiseq+(size_t)l*BH, wtf, spreb, l0,
                                           mx, mh, wmidih, wmidhh, f_bih_mid, f_bhh_mid,
                                           cmidf, mout, (l>=1)?1:0, (l==1)?1:0);
      k_sgemm<<<g816,b128,0,stream>>>(spreb, vdb, f_Vd_b, scoref);
      k_cellF<<<g816,b128,0,stream>>>(scoref, f_inp, l, hprev, wspih, wsphh,
                                      f_bih_sp, f_bhh_sp, cef, ceb, midb+(size_t)l*BH, l0);
    }
    // mid step 47 (x = he_47, hprev = hm_46)
    k_cell<<<g816,b128,0,stream>>>(midb+(size_t)47*BH, mid2b+(size_t)46*BH, wmidih, wmidhh,
                                   f_bih_mid, f_bhh_mid, cmidf, (u16*)nullptr,
                                   mid2b+(size_t)47*BH, 0);

    k_scgemm<<<dim3(384,16),b128,0,stream>>>(mid2b, wxb, f_Wx_b, whf, ttb);
    k_scred<<<dim3(Lenc*Bsz),dim3(64),0,stream>>>(ttb, f_V_w, f_V_b, scf);
    k_dec<<<dim3(Bsz),dim3(256),0,stream>>>(scf, mid2b, decb);

    u16* tmp=htR; htR=htW; htW=tmp;
  }
}